// Round 1
// baseline (3140.922 us; speedup 1.0000x reference)
//
#include <hip/hip_runtime.h>
#include <math.h>

// Problem constants (reference: B=4, S=2048, D_MODEL=HIDDEN=1024, H=16, d_k=64)
#define BB 4
#define SS 2048
#define DM 1024
#define NH 16
#define QCB 128              // q-rows per slab (per batch)
#define NSLAB (SS / QCB)     // 16

// Workspace layout (floats):
//   Qp, Kp, Vp, AO : 4 x B*S*DM     = 4 x 8388608 floats (32MB each)
//   Sc             : B*NH*QCB*SS    = 16777216 floats (64MB)
// total ~201 MB.

// ---------------- C[M,N] = A[M,K] @ W[N,K]^T + bias ----------------
// 128x128 tile, 256 threads, 8x8 microtile, k-major LDS (b128 reads).
__global__ __launch_bounds__(256) void gemm_nt(const float* __restrict__ A,
                                               const float* __restrict__ W,
                                               const float* __restrict__ bias,
                                               float* __restrict__ C,
                                               int M, int N, int K) {
  __shared__ float As[16][128];
  __shared__ float Bs[16][128];
  const int t  = threadIdx.x;
  const int tm = t >> 4, tn = t & 15;
  const int m0 = blockIdx.x * 128, n0 = blockIdx.y * 128;
  const int lr = t >> 1, lc = (t & 1) * 8;
  const float* Ap = A + (size_t)(m0 + lr) * K + lc;
  const float* Wp = W + (size_t)(n0 + lr) * K + lc;
  float acc[8][8];
#pragma unroll
  for (int i = 0; i < 8; ++i)
#pragma unroll
    for (int j = 0; j < 8; ++j) acc[i][j] = 0.f;

  for (int k0 = 0; k0 < K; k0 += 16) {
    float4 a0 = *(const float4*)(Ap + k0);
    float4 a1 = *(const float4*)(Ap + k0 + 4);
    float4 b0 = *(const float4*)(Wp + k0);
    float4 b1 = *(const float4*)(Wp + k0 + 4);
    __syncthreads();
    As[lc+0][lr]=a0.x; As[lc+1][lr]=a0.y; As[lc+2][lr]=a0.z; As[lc+3][lr]=a0.w;
    As[lc+4][lr]=a1.x; As[lc+5][lr]=a1.y; As[lc+6][lr]=a1.z; As[lc+7][lr]=a1.w;
    Bs[lc+0][lr]=b0.x; Bs[lc+1][lr]=b0.y; Bs[lc+2][lr]=b0.z; Bs[lc+3][lr]=b0.w;
    Bs[lc+4][lr]=b1.x; Bs[lc+5][lr]=b1.y; Bs[lc+6][lr]=b1.z; Bs[lc+7][lr]=b1.w;
    __syncthreads();
#pragma unroll
    for (int kk = 0; kk < 16; ++kk) {
      float4 x0 = *(const float4*)&As[kk][tm*8];
      float4 x1 = *(const float4*)&As[kk][tm*8+4];
      float4 y0 = *(const float4*)&Bs[kk][tn*8];
      float4 y1 = *(const float4*)&Bs[kk][tn*8+4];
      float xa[8] = {x0.x,x0.y,x0.z,x0.w,x1.x,x1.y,x1.z,x1.w};
      float yb[8] = {y0.x,y0.y,y0.z,y0.w,y1.x,y1.y,y1.z,y1.w};
#pragma unroll
      for (int i = 0; i < 8; ++i)
#pragma unroll
        for (int j = 0; j < 8; ++j) acc[i][j] += xa[i]*yb[j];
    }
  }
  float bv[8];
#pragma unroll
  for (int j = 0; j < 8; ++j) bv[j] = bias[n0 + tn*8 + j];
#pragma unroll
  for (int i = 0; i < 8; ++i) {
    size_t row = (size_t)(m0 + tm*8 + i) * N + n0 + tn*8;
    float4 o0 = {acc[i][0]+bv[0], acc[i][1]+bv[1], acc[i][2]+bv[2], acc[i][3]+bv[3]};
    float4 o1 = {acc[i][4]+bv[4], acc[i][5]+bv[5], acc[i][6]+bv[6], acc[i][7]+bv[7]};
    *(float4*)(C + row)     = o0;
    *(float4*)(C + row + 4) = o1;
  }
}

// -------- scores: Sc[bh][qq][k] = 0.125 * dot64(Qp[q], Kp[k]) per head --------
// grid (S/64 k-tiles, QCB/32 q-tiles, B*NH); block 256.
__global__ __launch_bounds__(256) void scores_k(const float* __restrict__ Qp,
                                                const float* __restrict__ Kp,
                                                float* __restrict__ Sc,
                                                int q0) {
  __shared__ float Qs[64][32];   // [d][q]
  __shared__ float Ks[64][64];   // [d][k]
  const int t   = threadIdx.x;
  const int bh  = blockIdx.z;           // b*16 + h
  const int b   = bh >> 4, h = bh & 15;
  const int k0  = blockIdx.x * 64;
  const int qq0 = blockIdx.y * 32;
  {
    int i  = t >> 3;           // q row 0..31
    int d0 = (t & 7) * 8;
    const float* src = Qp + ((size_t)b*SS + q0 + qq0 + i) * DM + h*64 + d0;
    float4 v0 = *(const float4*)src;
    float4 v1 = *(const float4*)(src + 4);
    Qs[d0+0][i]=v0.x; Qs[d0+1][i]=v0.y; Qs[d0+2][i]=v0.z; Qs[d0+3][i]=v0.w;
    Qs[d0+4][i]=v1.x; Qs[d0+5][i]=v1.y; Qs[d0+6][i]=v1.z; Qs[d0+7][i]=v1.w;
  }
  {
    int kk = t >> 2;           // k row 0..63
    int d0 = (t & 3) * 16;
    const float* src = Kp + ((size_t)b*SS + k0 + kk) * DM + h*64 + d0;
#pragma unroll
    for (int j4 = 0; j4 < 4; ++j4) {
      float4 v = *(const float4*)(src + j4*4);
      Ks[d0+j4*4+0][kk]=v.x; Ks[d0+j4*4+1][kk]=v.y;
      Ks[d0+j4*4+2][kk]=v.z; Ks[d0+j4*4+3][kk]=v.w;
    }
  }
  __syncthreads();
  const int tq = t >> 5;   // 0..7  -> q = qq0 + tq*4 + i
  const int tk = t & 31;   // k = k0 + tk*2 + j
  float acc[4][2] = {{0.f,0.f},{0.f,0.f},{0.f,0.f},{0.f,0.f}};
#pragma unroll
  for (int d = 0; d < 64; ++d) {
    float4 qa = *(const float4*)&Qs[d][tq*4];
    float2 kb = *(const float2*)&Ks[d][tk*2];
    acc[0][0] += qa.x*kb.x; acc[0][1] += qa.x*kb.y;
    acc[1][0] += qa.y*kb.x; acc[1][1] += qa.y*kb.y;
    acc[2][0] += qa.z*kb.x; acc[2][1] += qa.z*kb.y;
    acc[3][0] += qa.w*kb.x; acc[3][1] += qa.w*kb.y;
  }
#pragma unroll
  for (int i = 0; i < 4; ++i) {
    size_t idx = ((size_t)bh*QCB + qq0 + tq*4 + i) * SS + k0 + tk*2;
    float2 o = { acc[i][0]*0.125f, acc[i][1]*0.125f };
    *(float2*)(Sc + idx) = o;
  }
}

// ------ double softmax over the HEADS axis (16 values per (b,qq,k)), in place ------
__global__ __launch_bounds__(256) void softmax_h(float* __restrict__ Sc) {
  const size_t HS    = (size_t)QCB * SS;   // per-(b,h) plane
  const size_t total = (size_t)BB * HS;    // (b,qq,k) fibers
  for (size_t gid = (size_t)blockIdx.x*256 + threadIdx.x; gid < total;
       gid += (size_t)gridDim.x*256) {
    size_t b   = gid / HS;
    size_t rem = gid - b*HS;
    float* base = Sc + (b*NH)*HS + rem;
    float x[16];
#pragma unroll
    for (int h = 0; h < 16; ++h) x[h] = base[h*HS];
    float m = x[0];
#pragma unroll
    for (int h = 1; h < 16; ++h) m = fmaxf(m, x[h]);
    float s = 0.f;
#pragma unroll
    for (int h = 0; h < 16; ++h) { x[h] = expf(x[h] - m); s += x[h]; }
    float inv = 1.f / s;
    // second softmax of (x*inv*0.125): exponent arg = (x[h]-max_x)*inv*0.125
    float m2 = x[0];
#pragma unroll
    for (int h = 1; h < 16; ++h) m2 = fmaxf(m2, x[h]);
    float s2 = 0.f;
#pragma unroll
    for (int h = 0; h < 16; ++h) { x[h] = expf((x[h] - m2) * inv * 0.125f); s2 += x[h]; }
    float inv2 = 1.f / s2;
#pragma unroll
    for (int h = 0; h < 16; ++h) base[h*HS] = x[h] * inv2;
  }
}

// -------- PV: AO[b][q][h*64+d] = sum_k w[bh][qq][k] * Vp[b][k][h*64+d] --------
// grid (B*NH, QCB/32); block 256; k-chunks of 32.
__global__ __launch_bounds__(256) void pv_k(const float* __restrict__ Sc,
                                            const float* __restrict__ Vp,
                                            float* __restrict__ AO,
                                            int q0) {
  __shared__ float Ws[32][33];   // [q][k] (+1 pad)
  __shared__ float Vs[32][64];   // [k][d]
  const int t   = threadIdx.x;
  const int bh  = blockIdx.x;
  const int b   = bh >> 4, h = bh & 15;
  const int qq0 = blockIdx.y * 32;
  const int tq  = t >> 4;        // 0..15 -> q = tq*2 + i
  const int tk  = t & 15;        // d = tk*4 + j
  const int wi  = t >> 3;        // 0..31
  const int wk  = (t & 7) * 4;
  const int vk  = t >> 3;        // 0..31
  const int vd  = (t & 7) * 8;
  float acc[2][4] = {{0,0,0,0},{0,0,0,0}};
  for (int k0 = 0; k0 < SS; k0 += 32) {
    float4 wv = *(const float4*)(Sc + ((size_t)bh*QCB + qq0 + wi)*SS + k0 + wk);
    const float* vsrc = Vp + ((size_t)b*SS + k0 + vk)*DM + h*64 + vd;
    float4 v0 = *(const float4*)vsrc;
    float4 v1 = *(const float4*)(vsrc + 4);
    __syncthreads();
    Ws[wi][wk+0]=wv.x; Ws[wi][wk+1]=wv.y; Ws[wi][wk+2]=wv.z; Ws[wi][wk+3]=wv.w;
    *(float4*)&Vs[vk][vd]   = v0;
    *(float4*)&Vs[vk][vd+4] = v1;
    __syncthreads();
#pragma unroll
    for (int kk = 0; kk < 32; ++kk) {
      float w0 = Ws[tq*2+0][kk];
      float w1 = Ws[tq*2+1][kk];
      float4 vv = *(const float4*)&Vs[kk][tk*4];
      acc[0][0]+=w0*vv.x; acc[0][1]+=w0*vv.y; acc[0][2]+=w0*vv.z; acc[0][3]+=w0*vv.w;
      acc[1][0]+=w1*vv.x; acc[1][1]+=w1*vv.y; acc[1][2]+=w1*vv.z; acc[1][3]+=w1*vv.w;
    }
  }
#pragma unroll
  for (int i = 0; i < 2; ++i) {
    float4 o = {acc[i][0],acc[i][1],acc[i][2],acc[i][3]};
    *(float4*)(AO + ((size_t)b*SS + q0 + qq0 + tq*2 + i)*DM + h*64 + tk*4) = o;
  }
}

extern "C" void kernel_launch(void* const* d_in, const int* in_sizes, int n_in,
                              void* d_out, int out_size, void* d_ws, size_t ws_size,
                              hipStream_t stream) {
  // setup_inputs order: k, q, v, Wq, bq, Wk, bk, Wv, bv, Wo, bo  (all fp32)
  const float* kin = (const float*)d_in[0];
  const float* qin = (const float*)d_in[1];
  const float* vin = (const float*)d_in[2];
  const float* Wq  = (const float*)d_in[3];
  const float* bq  = (const float*)d_in[4];
  const float* Wk  = (const float*)d_in[5];
  const float* bk  = (const float*)d_in[6];
  const float* Wv  = (const float*)d_in[7];
  const float* bv  = (const float*)d_in[8];
  const float* Wo  = (const float*)d_in[9];
  const float* bo  = (const float*)d_in[10];
  float* out = (float*)d_out;
  float* ws  = (float*)d_ws;

  const size_t P = (size_t)BB * SS * DM;   // 8388608
  float* Qp = ws;
  float* Kp = Qp + P;
  float* Vp = Kp + P;
  float* AO = Vp + P;
  float* Sc = AO + P;                      // BB*NH*QCB*SS floats (64MB)

  dim3 gg(8192/128, 1024/128);
  gemm_nt<<<gg, 256, 0, stream>>>(qin, Wq, bq, Qp, 8192, 1024, 1024);
  gemm_nt<<<gg, 256, 0, stream>>>(kin, Wk, bk, Kp, 8192, 1024, 1024);
  gemm_nt<<<gg, 256, 0, stream>>>(vin, Wv, bv, Vp, 8192, 1024, 1024);

  for (int slab = 0; slab < NSLAB; ++slab) {
    int q0 = slab * QCB;
    scores_k<<<dim3(SS/64, QCB/32, BB*NH), 256, 0, stream>>>(Qp, Kp, Sc, q0);
    softmax_h<<<dim3(2048), 256, 0, stream>>>(Sc);
    pv_k<<<dim3(BB*NH, QCB/32), 256, 0, stream>>>(Sc, Vp, AO, q0);
  }

  gemm_nt<<<gg, 256, 0, stream>>>(AO, Wo, bo, out, 8192, 1024, 1024);
}

// Round 2
// 834.286 us; speedup vs baseline: 3.7648x; 3.7648x over previous
//
#include <hip/hip_runtime.h>
#include <math.h>

#define BB 4
#define SS 2048
#define DM 1024
#define NH 16
#define QCB 256
#define NSLAB (SS / QCB)   // 8

typedef unsigned short u16;
typedef __attribute__((ext_vector_type(8))) short bf16x8;
typedef __attribute__((ext_vector_type(4))) float f32x4;

__device__ __forceinline__ u16 f2bf(float f) {
  union { float f; unsigned u; } v; v.f = f;
  unsigned r = v.u + 0x7fffu + ((v.u >> 16) & 1u);
  return (u16)(r >> 16);
}
__device__ __forceinline__ float bf2f(u16 h) {
  union { unsigned u; float f; } v; v.u = ((unsigned)h) << 16;
  return v.f;
}
// async global->LDS, 16B per lane; LDS dest is wave-uniform base + lane*16
__device__ __forceinline__ void gl16(const u16* g, u16* l) {
  __builtin_amdgcn_global_load_lds((__attribute__((address_space(1))) void*)(u16*)g,
                                   (__attribute__((address_space(3))) void*)l, 16, 0, 0);
}

// ---------------- fp32 -> bf16 conversion, 8 elems/thread ----------------
__global__ __launch_bounds__(256) void cvt_bf16(const float* __restrict__ in,
                                                u16* __restrict__ out, int n8) {
  int i = blockIdx.x * 256 + threadIdx.x;
  if (i >= n8) return;
  const float4* p = (const float4*)in + (size_t)i * 2;
  float4 a = p[0], b = p[1];
  ushort4 o0 = { f2bf(a.x), f2bf(a.y), f2bf(a.z), f2bf(a.w) };
  ushort4 o1 = { f2bf(b.x), f2bf(b.y), f2bf(b.z), f2bf(b.w) };
  ushort4* q = (ushort4*)out + (size_t)i * 2;
  q[0] = o0; q[1] = o1;
}

// ---------------- C[M,N] = A[M,K] @ W[N,K]^T + bias (bf16 MFMA, m97-style) ----
// MODE 0: bf16 row-major C.  MODE 1: bf16 scatter to Vt[b,h,d,s].  MODE 2: fp32 C.
template <int MODE>
__global__ __launch_bounds__(256) void gemm_proj(const u16* __restrict__ A,
                                                 const u16* __restrict__ W,
                                                 const float* __restrict__ bias,
                                                 void* __restrict__ Cv,
                                                 int M, int N, int K) {
  __shared__ __align__(16) u16 As[128 * 32];
  __shared__ __align__(16) u16 Bs[128 * 32];
  const int t = threadIdx.x;
  const int w = t >> 6, l = t & 63;
  const int m0 = blockIdx.x * 128, n0 = blockIdx.y * 128;
  const int wm = (w >> 1) * 64, wn = (w & 1) * 64;
  const int lr = l & 15, lg = (l >> 4) * 8;
  const int sr = t >> 2, sc4 = (t & 3) * 8;   // staging: chunk t -> row t>>2, col (t&3)*8

  const u16* Ap1 = A + (size_t)(m0 + sr) * K + sc4;
  const u16* Ap2 = Ap1 + (size_t)64 * K;
  const u16* Wp1 = W + (size_t)(n0 + sr) * K + sc4;
  const u16* Wp2 = Wp1 + (size_t)64 * K;
  u16* Asd1 = As + w * 512;
  u16* Asd2 = As + 2048 + w * 512;
  u16* Bsd1 = Bs + w * 512;
  u16* Bsd2 = Bs + 2048 + w * 512;

  f32x4 acc[4][4];
  f32x4 z4 = {0.f, 0.f, 0.f, 0.f};
#pragma unroll
  for (int i = 0; i < 4; ++i)
#pragma unroll
    for (int j = 0; j < 4; ++j) acc[i][j] = z4;

  for (int k0 = 0; k0 < K; k0 += 32) {
    __syncthreads();
    gl16(Ap1 + k0, Asd1);
    gl16(Ap2 + k0, Asd2);
    gl16(Wp1 + k0, Bsd1);
    gl16(Wp2 + k0, Bsd2);
    __syncthreads();
    bf16x8 af[4], bw[4];
#pragma unroll
    for (int i = 0; i < 4; ++i) {
      af[i] = *(const bf16x8*)&As[(wm + i * 16 + lr) * 32 + lg];
      bw[i] = *(const bf16x8*)&Bs[(wn + i * 16 + lr) * 32 + lg];
    }
#pragma unroll
    for (int i = 0; i < 4; ++i)
#pragma unroll
      for (int j = 0; j < 4; ++j)
        acc[i][j] = __builtin_amdgcn_mfma_f32_16x16x32_bf16(af[i], bw[j], acc[i][j], 0, 0, 0);
  }

  const int lg4 = (l >> 4) * 4;
#pragma unroll
  for (int j = 0; j < 4; ++j) {
    const int col = n0 + wn + j * 16 + lr;
    const float bj = bias[col];
#pragma unroll
    for (int i = 0; i < 4; ++i) {
#pragma unroll
      for (int r = 0; r < 4; ++r) {
        const int row = m0 + wm + i * 16 + lg4 + r;
        const float val = acc[i][j][r] + bj;
        if (MODE == 0) {
          ((u16*)Cv)[(size_t)row * N + col] = f2bf(val);
        } else if (MODE == 1) {
          // Vt[((b*16+h)*64+d)*SS + s]
          ((u16*)Cv)[((size_t)((row >> 11) * 16 + (col >> 6)) * 64 + (col & 63)) * SS +
                     (row & 2047)] = f2bf(val);
        } else {
          ((float*)Cv)[(size_t)row * N + col] = val;
        }
      }
    }
  }
}

// ------- scores: Sc[bh][q][k_] = 0.125 * dot64(Qp_h[q], Kp_h[k_])  (bf16 MFMA) -----
__global__ __launch_bounds__(256) void gemm_scores(const u16* __restrict__ Qp,
                                                   const u16* __restrict__ Kp,
                                                   u16* __restrict__ Sc, int q0) {
  __shared__ __align__(16) u16 As[128 * 32];
  __shared__ __align__(16) u16 Bs[128 * 32];
  const int t = threadIdx.x, w = t >> 6, l = t & 63;
  const int bh = blockIdx.z, b = bh >> 4, h = bh & 15;
  const int m0 = blockIdx.y * 128;     // q within slab
  const int n0 = blockIdx.x * 128;     // k_
  const int wm = (w >> 1) * 64, wn = (w & 1) * 64;
  const int lr = l & 15, lg = (l >> 4) * 8;
  const int sr = t >> 2, sc4 = (t & 3) * 8;
  const u16* Ap1 = Qp + ((size_t)b * SS + q0 + m0 + sr) * DM + h * 64 + sc4;
  const u16* Ap2 = Ap1 + (size_t)64 * DM;
  const u16* Bp1 = Kp + ((size_t)b * SS + n0 + sr) * DM + h * 64 + sc4;
  const u16* Bp2 = Bp1 + (size_t)64 * DM;
  u16* Asd1 = As + w * 512;
  u16* Asd2 = As + 2048 + w * 512;
  u16* Bsd1 = Bs + w * 512;
  u16* Bsd2 = Bs + 2048 + w * 512;

  f32x4 acc[4][4];
  f32x4 z4 = {0.f, 0.f, 0.f, 0.f};
#pragma unroll
  for (int i = 0; i < 4; ++i)
#pragma unroll
    for (int j = 0; j < 4; ++j) acc[i][j] = z4;

  for (int k0 = 0; k0 < 64; k0 += 32) {
    __syncthreads();
    gl16(Ap1 + k0, Asd1);
    gl16(Ap2 + k0, Asd2);
    gl16(Bp1 + k0, Bsd1);
    gl16(Bp2 + k0, Bsd2);
    __syncthreads();
    bf16x8 af[4], bw[4];
#pragma unroll
    for (int i = 0; i < 4; ++i) {
      af[i] = *(const bf16x8*)&As[(wm + i * 16 + lr) * 32 + lg];
      bw[i] = *(const bf16x8*)&Bs[(wn + i * 16 + lr) * 32 + lg];
    }
#pragma unroll
    for (int i = 0; i < 4; ++i)
#pragma unroll
      for (int j = 0; j < 4; ++j)
        acc[i][j] = __builtin_amdgcn_mfma_f32_16x16x32_bf16(af[i], bw[j], acc[i][j], 0, 0, 0);
  }

  const int lg4 = (l >> 4) * 4;
  u16* Cb = Sc + (size_t)bh * ((size_t)QCB * SS);
#pragma unroll
  for (int i = 0; i < 4; ++i)
#pragma unroll
    for (int j = 0; j < 4; ++j)
#pragma unroll
      for (int r = 0; r < 4; ++r)
        Cb[(size_t)(m0 + wm + i * 16 + lg4 + r) * SS + (n0 + wn + j * 16 + lr)] =
            f2bf(acc[i][j][r] * 0.125f);
}

// ------ double softmax over HEADS (16 values, stride = QCB*SS), bf16 in/out ------
__global__ __launch_bounds__(256) void softmax_h(u16* __restrict__ Sc) {
  const size_t HS = (size_t)QCB * SS;
  const size_t n4 = (size_t)BB * HS / 4;
  for (size_t gid = (size_t)blockIdx.x * 256 + threadIdx.x; gid < n4;
       gid += (size_t)gridDim.x * 256) {
    const size_t b = gid / (HS / 4);
    const size_t rem = (gid - b * (HS / 4)) * 4;
    u16* base = Sc + b * NH * HS + rem;
    float x[4][16];
#pragma unroll
    for (int h = 0; h < 16; ++h) {
      ushort4 r4 = *(const ushort4*)(base + (size_t)h * HS);
      x[0][h] = bf2f(r4.x); x[1][h] = bf2f(r4.y);
      x[2][h] = bf2f(r4.z); x[3][h] = bf2f(r4.w);
    }
#pragma unroll
    for (int v = 0; v < 4; ++v) {
      float m = x[v][0];
#pragma unroll
      for (int h = 1; h < 16; ++h) m = fmaxf(m, x[v][h]);
      float s = 0.f;
#pragma unroll
      for (int h = 0; h < 16; ++h) { x[v][h] = __expf(x[v][h] - m); s += x[v][h]; }
      const float inv = 0.125f / s;       // folds second scale
      float m2 = x[v][0];
#pragma unroll
      for (int h = 1; h < 16; ++h) m2 = fmaxf(m2, x[v][h]);
      float s2 = 0.f;
#pragma unroll
      for (int h = 0; h < 16; ++h) { x[v][h] = __expf((x[v][h] - m2) * inv); s2 += x[v][h]; }
      const float inv2 = 1.f / s2;
#pragma unroll
      for (int h = 0; h < 16; ++h) x[v][h] *= inv2;
    }
#pragma unroll
    for (int h = 0; h < 16; ++h) {
      ushort4 o4 = { f2bf(x[0][h]), f2bf(x[1][h]), f2bf(x[2][h]), f2bf(x[3][h]) };
      *(ushort4*)(base + (size_t)h * HS) = o4;
    }
  }
}

// ---- PV: AO[b, q0+q, h*64+d] = sum_k W[bh,q,k] * Vt[bh,d,k]   (bf16 MFMA) ----
__global__ __launch_bounds__(256) void gemm_pv(const u16* __restrict__ Sc,
                                               const u16* __restrict__ Vt,
                                               u16* __restrict__ AO, int q0) {
  __shared__ __align__(16) u16 As[64 * 32];
  __shared__ __align__(16) u16 Bs[64 * 32];
  const int t = threadIdx.x, w = t >> 6, l = t & 63;
  const int bh = blockIdx.y, b = bh >> 4, h = bh & 15;
  const int m0 = blockIdx.x * 64;          // q-tile within slab
  const int wm = (w >> 1) * 32, wn = (w & 1) * 32;
  const int lr = l & 15, lg = (l >> 4) * 8;
  const int sr = t >> 2, sc4 = (t & 3) * 8;
  const u16* Ap = Sc + (size_t)bh * ((size_t)QCB * SS) + (size_t)(m0 + sr) * SS + sc4;
  const u16* Bp = Vt + ((size_t)bh * 64 + sr) * SS + sc4;
  u16* Asd = As + w * 512;
  u16* Bsd = Bs + w * 512;

  f32x4 acc[2][2];
  f32x4 z4 = {0.f, 0.f, 0.f, 0.f};
#pragma unroll
  for (int i = 0; i < 2; ++i)
#pragma unroll
    for (int j = 0; j < 2; ++j) acc[i][j] = z4;

  for (int k0 = 0; k0 < SS; k0 += 32) {
    __syncthreads();
    gl16(Ap + k0, Asd);
    gl16(Bp + k0, Bsd);
    __syncthreads();
    bf16x8 af[2], bv[2];
#pragma unroll
    for (int i = 0; i < 2; ++i) {
      af[i] = *(const bf16x8*)&As[(wm + i * 16 + lr) * 32 + lg];
      bv[i] = *(const bf16x8*)&Bs[(wn + i * 16 + lr) * 32 + lg];
    }
#pragma unroll
    for (int i = 0; i < 2; ++i)
#pragma unroll
      for (int j = 0; j < 2; ++j)
        acc[i][j] = __builtin_amdgcn_mfma_f32_16x16x32_bf16(af[i], bv[j], acc[i][j], 0, 0, 0);
  }

  const int lg4 = (l >> 4) * 4;
#pragma unroll
  for (int i = 0; i < 2; ++i)
#pragma unroll
    for (int j = 0; j < 2; ++j)
#pragma unroll
      for (int r = 0; r < 4; ++r)
        AO[((size_t)b * SS + q0 + m0 + wm + i * 16 + lg4 + r) * DM + h * 64 + wn + j * 16 + lr] =
            f2bf(acc[i][j][r]);
}

extern "C" void kernel_launch(void* const* d_in, const int* in_sizes, int n_in,
                              void* d_out, int out_size, void* d_ws, size_t ws_size,
                              hipStream_t stream) {
  const float* kin = (const float*)d_in[0];
  const float* qin = (const float*)d_in[1];
  const float* vin = (const float*)d_in[2];
  const float* Wq  = (const float*)d_in[3];
  const float* bq  = (const float*)d_in[4];
  const float* Wk  = (const float*)d_in[5];
  const float* bk  = (const float*)d_in[6];
  const float* Wv  = (const float*)d_in[7];
  const float* bv  = (const float*)d_in[8];
  const float* Wo  = (const float*)d_in[9];
  const float* bo  = (const float*)d_in[10];

  const size_t P   = (size_t)BB * SS * DM;   // 8388608
  const size_t WSZ = (size_t)DM * DM;        // 1048576
  u16* Qb  = (u16*)d_ws;
  u16* Kb  = Qb + P;
  u16* Vb  = Kb + P;
  u16* Wqb = Vb + P;
  u16* Wkb = Wqb + WSZ;
  u16* Wvb = Wkb + WSZ;
  u16* Wob = Wvb + WSZ;
  u16* Qp  = Wob + WSZ;
  u16* Kp  = Qp + P;
  u16* Vt  = Kp + P;     // [bh][d][s]
  u16* AO  = Vt + P;
  u16* Sc  = AO + P;     // 32M elems = 64MB bf16

  cvt_bf16<<<dim3(4096), 256, 0, stream>>>(qin, Qb, (int)(P / 8));
  cvt_bf16<<<dim3(4096), 256, 0, stream>>>(kin, Kb, (int)(P / 8));
  cvt_bf16<<<dim3(4096), 256, 0, stream>>>(vin, Vb, (int)(P / 8));
  cvt_bf16<<<dim3(512), 256, 0, stream>>>(Wq, Wqb, (int)(WSZ / 8));
  cvt_bf16<<<dim3(512), 256, 0, stream>>>(Wk, Wkb, (int)(WSZ / 8));
  cvt_bf16<<<dim3(512), 256, 0, stream>>>(Wv, Wvb, (int)(WSZ / 8));
  cvt_bf16<<<dim3(512), 256, 0, stream>>>(Wo, Wob, (int)(WSZ / 8));

  dim3 gp(64, 8);
  gemm_proj<0><<<gp, 256, 0, stream>>>(Qb, Wqb, bq, Qp, 8192, 1024, 1024);
  gemm_proj<0><<<gp, 256, 0, stream>>>(Kb, Wkb, bk, Kp, 8192, 1024, 1024);
  gemm_proj<1><<<gp, 256, 0, stream>>>(Vb, Wvb, bv, Vt, 8192, 1024, 1024);

  for (int s = 0; s < NSLAB; ++s) {
    const int q0 = s * QCB;
    gemm_scores<<<dim3(16, 2, 64), 256, 0, stream>>>(Qp, Kp, Sc, q0);
    softmax_h<<<dim3(2048), 256, 0, stream>>>(Sc);
    gemm_pv<<<dim3(4, 64), 256, 0, stream>>>(Sc, Vt, AO, q0);
  }

  gemm_proj<2><<<gp, 256, 0, stream>>>(AO, Wob, bo, (float*)d_out, 8192, 1024, 1024);
}

// Round 5
// 702.210 us; speedup vs baseline: 4.4729x; 1.1881x over previous
//
#include <hip/hip_runtime.h>
#include <math.h>

#define BB 4
#define SS 2048
#define DM 1024
#define NH 16

typedef unsigned short u16;
typedef __attribute__((ext_vector_type(8))) short bf16x8;
typedef __attribute__((ext_vector_type(4))) float f32x4;

__device__ __forceinline__ u16 f2bf(float f) {
  union { float f; unsigned u; } v; v.f = f;
  unsigned r = v.u + 0x7fffu + ((v.u >> 16) & 1u);
  return (u16)(r >> 16);
}
__device__ __forceinline__ float bf2f(u16 h) {
  union { unsigned u; float f; } v; v.u = ((unsigned)h) << 16;
  return v.f;
}
__device__ __forceinline__ void gl16(const u16* g, u16* l) {
  __builtin_amdgcn_global_load_lds((__attribute__((address_space(1))) void*)(u16*)g,
                                   (__attribute__((address_space(3))) void*)l, 16, 0, 0);
}

// ---------------- fp32 -> bf16 conversion, 8 elems/thread ----------------
__global__ __launch_bounds__(256) void cvt_bf16(const float* __restrict__ in,
                                                u16* __restrict__ out, int n8) {
  int i = blockIdx.x * 256 + threadIdx.x;
  if (i >= n8) return;
  const float4* p = (const float4*)in + (size_t)i * 2;
  float4 a = p[0], b = p[1];
  ushort4 o0 = { f2bf(a.x), f2bf(a.y), f2bf(a.z), f2bf(a.w) };
  ushort4 o1 = { f2bf(b.x), f2bf(b.y), f2bf(b.z), f2bf(b.w) };
  ushort4* q = (ushort4*)out + (size_t)i * 2;
  q[0] = o0; q[1] = o1;
}

// ---------------- C[M,N] = A[M,K] @ W[N,K]^T + bias (bf16 MFMA) ----
// MODE 0: bf16 row-major C.  MODE 1: bf16 scatter to Vt[b,h,d,s].  MODE 2: fp32 C.
template <int MODE>
__global__ __launch_bounds__(256) void gemm_proj(const u16* __restrict__ A,
                                                 const u16* __restrict__ W,
                                                 const float* __restrict__ bias,
                                                 void* __restrict__ Cv,
                                                 int M, int N, int K) {
  __shared__ __align__(16) u16 As[128 * 32];
  __shared__ __align__(16) u16 Bs[128 * 32];
  const int t = threadIdx.x;
  const int w = t >> 6, l = t & 63;
  const int m0 = blockIdx.x * 128, n0 = blockIdx.y * 128;
  const int wm = (w >> 1) * 64, wn = (w & 1) * 64;
  const int lr = l & 15, lg = (l >> 4) * 8;
  const int sr = t >> 2, sc4 = (t & 3) * 8;

  const u16* Ap1 = A + (size_t)(m0 + sr) * K + sc4;
  const u16* Ap2 = Ap1 + (size_t)64 * K;
  const u16* Wp1 = W + (size_t)(n0 + sr) * K + sc4;
  const u16* Wp2 = Wp1 + (size_t)64 * K;
  u16* Asd1 = As + w * 512;
  u16* Asd2 = As + 2048 + w * 512;
  u16* Bsd1 = Bs + w * 512;
  u16* Bsd2 = Bs + 2048 + w * 512;

  f32x4 acc[4][4];
  f32x4 z4 = {0.f, 0.f, 0.f, 0.f};
#pragma unroll
  for (int i = 0; i < 4; ++i)
#pragma unroll
    for (int j = 0; j < 4; ++j) acc[i][j] = z4;

  for (int k0 = 0; k0 < K; k0 += 32) {
    __syncthreads();
    gl16(Ap1 + k0, Asd1);
    gl16(Ap2 + k0, Asd2);
    gl16(Wp1 + k0, Bsd1);
    gl16(Wp2 + k0, Bsd2);
    __syncthreads();
    bf16x8 af[4], bw[4];
#pragma unroll
    for (int i = 0; i < 4; ++i) {
      af[i] = *(const bf16x8*)&As[(wm + i * 16 + lr) * 32 + lg];
      bw[i] = *(const bf16x8*)&Bs[(wn + i * 16 + lr) * 32 + lg];
    }
#pragma unroll
    for (int i = 0; i < 4; ++i)
#pragma unroll
      for (int j = 0; j < 4; ++j)
        acc[i][j] = __builtin_amdgcn_mfma_f32_16x16x32_bf16(af[i], bw[j], acc[i][j], 0, 0, 0);
  }

  const int lg4 = (l >> 4) * 4;
#pragma unroll
  for (int j = 0; j < 4; ++j) {
    const int col = n0 + wn + j * 16 + lr;
    const float bj = bias[col];
#pragma unroll
    for (int i = 0; i < 4; ++i) {
#pragma unroll
      for (int r = 0; r < 4; ++r) {
        const int row = m0 + wm + i * 16 + lg4 + r;
        const float val = acc[i][j][r] + bj;
        if (MODE == 0) {
          ((u16*)Cv)[(size_t)row * N + col] = f2bf(val);
        } else if (MODE == 1) {
          ((u16*)Cv)[((size_t)((row >> 11) * 16 + (col >> 6)) * 64 + (col & 63)) * SS +
                     (row & 2047)] = f2bf(val);
        } else {
          ((float*)Cv)[(size_t)row * N + col] = val;
        }
      }
    }
  }
}

// -------- double softmax over 16 heads, lane-local fiber --------
// After pass 1, max_h exp(x-m) == 1.0 exactly (argmax gives exp(0)), so the
// second pass needs no max scan: x <- exp((x - 1) * 0.125/s).
__device__ __forceinline__ void dsm16(float x[16]) {
  float m = x[0];
#pragma unroll
  for (int h = 1; h < 16; ++h) m = fmaxf(m, x[h]);
  float s = 0.f;
#pragma unroll
  for (int h = 0; h < 16; ++h) { x[h] = __expf(x[h] - m); s += x[h]; }
  const float inv = 0.125f / s;
  float s2 = 0.f;
#pragma unroll
  for (int h = 0; h < 16; ++h) { x[h] = __expf((x[h] - 1.0f) * inv); s2 += x[h]; }
  const float inv2 = 1.f / s2;
#pragma unroll
  for (int h = 0; h < 16; ++h) x[h] *= inv2;
}

// ===== fused attention: scores (all 16 h) -> h-softmax^2 -> PV, per (b, 32q) =====
// 512 threads = 8 waves; wave w owns heads {2w, 2w+1}. k-loop in steps of 32.
// Scores computed SWAPPED (mfma(K,Q)) so each lane holds 4 consecutive k for a
// fixed q -> Ws spill is 8 ds_write_b64 per wave (was 32 scalar ds_write_b16).
__global__ __launch_bounds__(512, 2) void fused_attn(const u16* __restrict__ Qp,
                                                     const u16* __restrict__ Kp,
                                                     const u16* __restrict__ Vt,
                                                     u16* __restrict__ AO) {
  __shared__ __align__(16) u16 Ks[32 * 1024];     // [k][d], chunk-XOR-swizzled per row
  __shared__ __align__(16) u16 Vs[1024 * 32];     // [d_glob][k], k-contiguous
  __shared__ __align__(16) u16 Ws[16 * 32 * 32];  // [h][q][k]

  const int t = threadIdx.x;
  const int w = t >> 6, l = t & 63;
  const int lr = l & 15, lg = l >> 4;          // frag row (0..15), chunk (0..3)
  const int bid = blockIdx.x;
  // XCD-pinning: xcd = bid&7 -> batch b = xcd>>1; q-half = xcd&1
  const int xcd = bid & 7;
  const int b = xcd >> 1;
  const int qt = (xcd & 1) * 32 + (bid >> 3);  // 0..63
  const int q0 = qt * 32;
  const int h0 = w * 2;

  // hoisted Q fragments: [hh][msub][dchunk]
  bf16x8 qf[2][2][2];
#pragma unroll
  for (int hh = 0; hh < 2; ++hh)
#pragma unroll
    for (int m = 0; m < 2; ++m)
#pragma unroll
      for (int dc = 0; dc < 2; ++dc)
        qf[hh][m][dc] = *(const bf16x8*)(Qp + ((size_t)b * SS + q0 + m * 16 + lr) * DM +
                                         (h0 + hh) * 64 + dc * 32 + lg * 8);

  f32x4 o[2][2][4];  // [hh][msub][dsub]
  f32x4 z4 = {0.f, 0.f, 0.f, 0.f};
#pragma unroll
  for (int hh = 0; hh < 2; ++hh)
#pragma unroll
    for (int m = 0; m < 2; ++m)
#pragma unroll
      for (int d = 0; d < 4; ++d) o[hh][m][d] = z4;

  const int sq = t >> 4;        // softmax fiber q (0..31)
  const int sk = t & 15;        // softmax fiber k-pair (0..15)

  for (int k0 = 0; k0 < SS; k0 += 32) {
    // ---- stage K (swizzled source -> linear LDS) and V ----
#pragma unroll
    for (int call = 0; call < 8; ++call) {
      const int p = call * 512 + t;          // chunk id (16B)
      const int r = p >> 7, c = p & 127;     // K row, phys chunk
      const int cg = (c & ~7) | ((c ^ r) & 7);
      gl16(Kp + ((size_t)b * SS + k0 + r) * DM + cg * 8, Ks + p * 8);
    }
#pragma unroll
    for (int call = 0; call < 8; ++call) {
      const int p = call * 512 + t;
      const int d = p >> 2, c = p & 3;
      gl16(Vt + ((size_t)b * 1024 + d) * SS + k0 + c * 8, Vs + p * 8);
    }
    __syncthreads();

    // ---- scores (SWAPPED): sa[hh][n][m] = K_tile^T-frag x Q-frag ----
    // per lane: q = m*16 + lr (fixed), k = n*16 + lg*4 + r (4 consecutive)
    f32x4 sa[2][2][2];
#pragma unroll
    for (int hh = 0; hh < 2; ++hh)
#pragma unroll
      for (int n = 0; n < 2; ++n)
#pragma unroll
        for (int m = 0; m < 2; ++m) sa[hh][n][m] = z4;
#pragma unroll
    for (int hh = 0; hh < 2; ++hh)
#pragma unroll
      for (int dc = 0; dc < 2; ++dc)
#pragma unroll
        for (int n = 0; n < 2; ++n) {
          const int row = n * 16 + lr;
          const int cl = (dc * 4 + lg) ^ (row & 7);
          bf16x8 kf = *(const bf16x8*)&Ks[row * 1024 + (h0 + hh) * 64 + cl * 8];
#pragma unroll
          for (int m = 0; m < 2; ++m)
            sa[hh][n][m] =
                __builtin_amdgcn_mfma_f32_16x16x32_bf16(kf, qf[hh][m][dc], sa[hh][n][m], 0, 0, 0);
        }
    // scaled scores -> Ws[h][q][k], vectorized ushort4 (4 consecutive k per lane)
#pragma unroll
    for (int hh = 0; hh < 2; ++hh)
#pragma unroll
      for (int n = 0; n < 2; ++n)
#pragma unroll
        for (int m = 0; m < 2; ++m) {
          ushort4 pk = { f2bf(sa[hh][n][m][0] * 0.125f), f2bf(sa[hh][n][m][1] * 0.125f),
                         f2bf(sa[hh][n][m][2] * 0.125f), f2bf(sa[hh][n][m][3] * 0.125f) };
          *(ushort4*)&Ws[(h0 + hh) * 1024 + (m * 16 + lr) * 32 + n * 16 + lg * 4] = pk;
        }
    __syncthreads();

    // ---- double h-softmax: each thread 2 fibers (ushort2) ----
    {
      u16* fib = Ws + sq * 32 + sk * 2;
      float xa[16], xb[16];
#pragma unroll
      for (int h = 0; h < 16; ++h) {
        const unsigned u = *(const unsigned*)(fib + h * 1024);
        xa[h] = bf2f((u16)(u & 0xffffu));
        xb[h] = bf2f((u16)(u >> 16));
      }
      dsm16(xa);
      dsm16(xb);
#pragma unroll
      for (int h = 0; h < 16; ++h)
        *(unsigned*)(fib + h * 1024) = (unsigned)f2bf(xa[h]) | ((unsigned)f2bf(xb[h]) << 16);
    }
    __syncthreads();

    // ---- PV: O += W @ V for this wave's 2 heads ----
#pragma unroll
    for (int hh = 0; hh < 2; ++hh) {
      bf16x8 aw[2];
#pragma unroll
      for (int m = 0; m < 2; ++m)
        aw[m] = *(const bf16x8*)&Ws[(h0 + hh) * 1024 + (m * 16 + lr) * 32 + lg * 8];
#pragma unroll
      for (int ds = 0; ds < 4; ++ds) {
        bf16x8 vf = *(const bf16x8*)&Vs[((h0 + hh) * 64 + ds * 16 + lr) * 32 + lg * 8];
#pragma unroll
        for (int m = 0; m < 2; ++m)
          o[hh][m][ds] =
              __builtin_amdgcn_mfma_f32_16x16x32_bf16(aw[m], vf, o[hh][m][ds], 0, 0, 0);
      }
    }
    __syncthreads();
  }

  // ---- epilogue: AO[b, q0+row, h*64+d] ----
#pragma unroll
  for (int hh = 0; hh < 2; ++hh)
#pragma unroll
    for (int m = 0; m < 2; ++m)
#pragma unroll
      for (int ds = 0; ds < 4; ++ds)
#pragma unroll
        for (int r = 0; r < 4; ++r)
          AO[((size_t)b * SS + q0 + m * 16 + lg * 4 + r) * DM + (h0 + hh) * 64 + ds * 16 + lr] =
              f2bf(o[hh][m][ds][r]);
}

extern "C" void kernel_launch(void* const* d_in, const int* in_sizes, int n_in,
                              void* d_out, int out_size, void* d_ws, size_t ws_size,
                              hipStream_t stream) {
  const float* kin = (const float*)d_in[0];
  const float* qin = (const float*)d_in[1];
  const float* vin = (const float*)d_in[2];
  const float* Wq  = (const float*)d_in[3];
  const float* bq  = (const float*)d_in[4];
  const float* Wk  = (const float*)d_in[5];
  const float* bk  = (const float*)d_in[6];
  const float* Wv  = (const float*)d_in[7];
  const float* bv  = (const float*)d_in[8];
  const float* Wo  = (const float*)d_in[9];
  const float* bo  = (const float*)d_in[10];

  const size_t P   = (size_t)BB * SS * DM;   // 8388608
  const size_t WSZ = (size_t)DM * DM;
  u16* Qb  = (u16*)d_ws;
  u16* Kb  = Qb + P;
  u16* Vb  = Kb + P;
  u16* Wqb = Vb + P;
  u16* Wkb = Wqb + WSZ;
  u16* Wvb = Wkb + WSZ;
  u16* Wob = Wvb + WSZ;
  u16* Qp  = Wob + WSZ;
  u16* Kp  = Qp + P;
  u16* Vt  = Kp + P;     // [b,h,d,s]
  u16* AO  = Vt + P;

  cvt_bf16<<<dim3(4096), 256, 0, stream>>>(qin, Qb, (int)(P / 8));
  cvt_bf16<<<dim3(4096), 256, 0, stream>>>(kin, Kb, (int)(P / 8));
  cvt_bf16<<<dim3(4096), 256, 0, stream>>>(vin, Vb, (int)(P / 8));
  cvt_bf16<<<dim3(512), 256, 0, stream>>>(Wq, Wqb, (int)(WSZ / 8));
  cvt_bf16<<<dim3(512), 256, 0, stream>>>(Wk, Wkb, (int)(WSZ / 8));
  cvt_bf16<<<dim3(512), 256, 0, stream>>>(Wv, Wvb, (int)(WSZ / 8));
  cvt_bf16<<<dim3(512), 256, 0, stream>>>(Wo, Wob, (int)(WSZ / 8));

  dim3 gp(64, 8);
  gemm_proj<0><<<gp, 256, 0, stream>>>(Qb, Wqb, bq, Qp, 8192, 1024, 1024);
  gemm_proj<0><<<gp, 256, 0, stream>>>(Kb, Wkb, bk, Kp, 8192, 1024, 1024);
  gemm_proj<1><<<gp, 256, 0, stream>>>(Vb, Wvb, bv, Vt, 8192, 1024, 1024);

  fused_attn<<<dim3(256), 512, 0, stream>>>(Qp, Kp, Vt, AO);

  gemm_proj<2><<<gp, 256, 0, stream>>>(AO, Wob, bo, (float*)d_out, 8192, 1024, 1024);
}

// Round 6
// 578.340 us; speedup vs baseline: 5.4309x; 1.2142x over previous
//
#include <hip/hip_runtime.h>
#include <math.h>

#define BB 4
#define SS 2048
#define DM 1024
#define NH 16

typedef unsigned short u16;
typedef __attribute__((ext_vector_type(8))) short bf16x8;
typedef __attribute__((ext_vector_type(4))) float f32x4;

__device__ __forceinline__ u16 f2bf(float f) {
  union { float f; unsigned u; } v; v.f = f;
  unsigned r = v.u + 0x7fffu + ((v.u >> 16) & 1u);
  return (u16)(r >> 16);
}
__device__ __forceinline__ float bf2f(u16 h) {
  union { unsigned u; float f; } v; v.u = ((unsigned)h) << 16;
  return v.f;
}
__device__ __forceinline__ void gl16(const u16* g, u16* l) {
  __builtin_amdgcn_global_load_lds((__attribute__((address_space(1))) void*)(u16*)g,
                                   (__attribute__((address_space(3))) void*)l, 16, 0, 0);
}

// ---------------- fp32 -> bf16 conversion, 8 elems/thread ----------------
__global__ __launch_bounds__(256) void cvt_bf16(const float* __restrict__ in,
                                                u16* __restrict__ out, int n8) {
  int i = blockIdx.x * 256 + threadIdx.x;
  if (i >= n8) return;
  const float4* p = (const float4*)in + (size_t)i * 2;
  float4 a = p[0], b = p[1];
  ushort4 o0 = { f2bf(a.x), f2bf(a.y), f2bf(a.z), f2bf(a.w) };
  ushort4 o1 = { f2bf(b.x), f2bf(b.y), f2bf(b.z), f2bf(b.w) };
  ushort4* q = (ushort4*)out + (size_t)i * 2;
  q[0] = o0; q[1] = o1;
}

// ---------------- C[M,N] = A[M,K] @ W[N,K]^T + bias (bf16 MFMA) ----
// MODE 0: bf16 row-major C.  MODE 1: bf16 scatter to Vt[b,h,d,s].  MODE 2: fp32 C.
template <int MODE>
__global__ __launch_bounds__(256) void gemm_proj(const u16* __restrict__ A,
                                                 const u16* __restrict__ W,
                                                 const float* __restrict__ bias,
                                                 void* __restrict__ Cv,
                                                 int M, int N, int K) {
  __shared__ __align__(16) u16 As[128 * 32];
  __shared__ __align__(16) u16 Bs[128 * 32];
  const int t = threadIdx.x;
  const int w = t >> 6, l = t & 63;
  const int m0 = blockIdx.x * 128, n0 = blockIdx.y * 128;
  const int wm = (w >> 1) * 64, wn = (w & 1) * 64;
  const int lr = l & 15, lg = (l >> 4) * 8;
  const int sr = t >> 2, sc4 = (t & 3) * 8;

  const u16* Ap1 = A + (size_t)(m0 + sr) * K + sc4;
  const u16* Ap2 = Ap1 + (size_t)64 * K;
  const u16* Wp1 = W + (size_t)(n0 + sr) * K + sc4;
  const u16* Wp2 = Wp1 + (size_t)64 * K;
  u16* Asd1 = As + w * 512;
  u16* Asd2 = As + 2048 + w * 512;
  u16* Bsd1 = Bs + w * 512;
  u16* Bsd2 = Bs + 2048 + w * 512;

  f32x4 acc[4][4];
  f32x4 z4 = {0.f, 0.f, 0.f, 0.f};
#pragma unroll
  for (int i = 0; i < 4; ++i)
#pragma unroll
    for (int j = 0; j < 4; ++j) acc[i][j] = z4;

  for (int k0 = 0; k0 < K; k0 += 32) {
    __syncthreads();
    gl16(Ap1 + k0, Asd1);
    gl16(Ap2 + k0, Asd2);
    gl16(Wp1 + k0, Bsd1);
    gl16(Wp2 + k0, Bsd2);
    __syncthreads();
    bf16x8 af[4], bw[4];
#pragma unroll
    for (int i = 0; i < 4; ++i) {
      af[i] = *(const bf16x8*)&As[(wm + i * 16 + lr) * 32 + lg];
      bw[i] = *(const bf16x8*)&Bs[(wn + i * 16 + lr) * 32 + lg];
    }
#pragma unroll
    for (int i = 0; i < 4; ++i)
#pragma unroll
      for (int j = 0; j < 4; ++j)
        acc[i][j] = __builtin_amdgcn_mfma_f32_16x16x32_bf16(af[i], bw[j], acc[i][j], 0, 0, 0);
  }

  const int lg4 = (l >> 4) * 4;
#pragma unroll
  for (int j = 0; j < 4; ++j) {
    const int col = n0 + wn + j * 16 + lr;
    const float bj = bias[col];
#pragma unroll
    for (int i = 0; i < 4; ++i) {
#pragma unroll
      for (int r = 0; r < 4; ++r) {
        const int row = m0 + wm + i * 16 + lg4 + r;
        const float val = acc[i][j][r] + bj;
        if (MODE == 0) {
          ((u16*)Cv)[(size_t)row * N + col] = f2bf(val);
        } else if (MODE == 1) {
          ((u16*)Cv)[((size_t)((row >> 11) * 16 + (col >> 6)) * 64 + (col & 63)) * SS +
                     (row & 2047)] = f2bf(val);
        } else {
          ((float*)Cv)[(size_t)row * N + col] = val;
        }
      }
    }
  }
}

// -------- double softmax over 16 heads, lane-local fiber --------
// After pass 1, max_h exp(x-m) == 1.0 exactly, so pass 2 needs no max scan.
__device__ __forceinline__ void dsm16(float x[16]) {
  float m = x[0];
#pragma unroll
  for (int h = 1; h < 16; ++h) m = fmaxf(m, x[h]);
  float s = 0.f;
#pragma unroll
  for (int h = 0; h < 16; ++h) { x[h] = __expf(x[h] - m); s += x[h]; }
  const float inv = 0.125f / s;
  float s2 = 0.f;
#pragma unroll
  for (int h = 0; h < 16; ++h) { x[h] = __expf((x[h] - 1.0f) * inv); s2 += x[h]; }
  const float inv2 = 1.f / s2;
#pragma unroll
  for (int h = 0; h < 16; ++h) x[h] *= inv2;
}

// ===== fused attention: scores -> h-softmax^2 -> PV, per (b, 32q) =====
// 8 waves; wave w owns heads {2w,2w+1}. k-step 32.
// K double-buffered in LDS (stage(t+1) issued under softmax phase);
// V read directly from global (Vt, L2-resident) into VGPRs at P1 start.
__global__ __launch_bounds__(512, 2) void fused_attn(const u16* __restrict__ Qp,
                                                     const u16* __restrict__ Kp,
                                                     const u16* __restrict__ Vt,
                                                     u16* __restrict__ AO) {
  __shared__ __align__(16) u16 Ks[2][32 * 1024];  // [buf][k][d], chunk-XOR-swizzled rows
  __shared__ __align__(16) u16 Ws[16 * 32 * 32];  // [h][q][k]

  const int t = threadIdx.x;
  const int w = t >> 6, l = t & 63;
  const int lr = l & 15, lg = l >> 4;          // frag row (0..15), chunk (0..3)
  const int bid = blockIdx.x;
  const int xcd = bid & 7;                     // XCD-pinning: batch per XCD-pair
  const int b = xcd >> 1;
  const int qt = (xcd & 1) * 32 + (bid >> 3);  // 0..63
  const int q0 = qt * 32;
  const int h0 = w * 2;

  // hoisted Q fragments
  bf16x8 qf[2][2][2];
#pragma unroll
  for (int hh = 0; hh < 2; ++hh)
#pragma unroll
    for (int m = 0; m < 2; ++m)
#pragma unroll
      for (int dc = 0; dc < 2; ++dc)
        qf[hh][m][dc] = *(const bf16x8*)(Qp + ((size_t)b * SS + q0 + m * 16 + lr) * DM +
                                         (h0 + hh) * 64 + dc * 32 + lg * 8);

  // K staging source pointers (8 chunks/thread), pre-swizzled; advance 32/step
  const u16* kaddr[8];
#pragma unroll
  for (int i = 0; i < 8; ++i) {
    const int p = i * 512 + t;
    const int r = p >> 7, c = p & 127;
    const int cg = (c & ~7) | ((c ^ r) & 7);
    kaddr[i] = Kp + ((size_t)b * SS + r) * DM + cg * 8;
  }
  // V fragment source pointers (8/thread); advance 32/step
  const u16* vp[8];
#pragma unroll
  for (int hh = 0; hh < 2; ++hh)
#pragma unroll
    for (int ds = 0; ds < 4; ++ds)
      vp[hh * 4 + ds] =
          Vt + (((size_t)b * 16 + h0 + hh) * 64 + ds * 16 + lr) * SS + lg * 8;

  f32x4 o[2][2][4];
  f32x4 z4 = {0.f, 0.f, 0.f, 0.f};
#pragma unroll
  for (int hh = 0; hh < 2; ++hh)
#pragma unroll
    for (int m = 0; m < 2; ++m)
#pragma unroll
      for (int d = 0; d < 4; ++d) o[hh][m][d] = z4;

  const int sq = t >> 4;   // softmax fiber q
  const int sk = t & 15;   // softmax fiber k-pair

  // prologue: stage tile 0 into buf 0
#pragma unroll
  for (int i = 0; i < 8; ++i) {
    gl16(kaddr[i], &Ks[0][0] + (i * 512 + t) * 8);
    kaddr[i] += 32;
  }
  __syncthreads();

  for (int tti = 0; tti < 64; ++tti) {
    const int cur = tti & 1;
    u16* KsC = &Ks[cur][0];
    u16* KsN = &Ks[cur ^ 1][0];

    // ---- P1: issue V frag loads (used in P3), scores, spill ----
    bf16x8 vfr[8];
#pragma unroll
    for (int i = 0; i < 8; ++i) {
      vfr[i] = *(const bf16x8*)vp[i];
      vp[i] += 32;
    }

    f32x4 sa[2][2][2];
#pragma unroll
    for (int hh = 0; hh < 2; ++hh)
#pragma unroll
      for (int n = 0; n < 2; ++n)
#pragma unroll
        for (int m = 0; m < 2; ++m) sa[hh][n][m] = z4;
#pragma unroll
    for (int hh = 0; hh < 2; ++hh)
#pragma unroll
      for (int dc = 0; dc < 2; ++dc)
#pragma unroll
        for (int n = 0; n < 2; ++n) {
          const int row = n * 16 + lr;
          const int cl = (dc * 4 + lg) ^ (row & 7);
          bf16x8 kf = *(const bf16x8*)&KsC[row * 1024 + (h0 + hh) * 64 + cl * 8];
#pragma unroll
          for (int m = 0; m < 2; ++m)
            sa[hh][n][m] =
                __builtin_amdgcn_mfma_f32_16x16x32_bf16(kf, qf[hh][m][dc], sa[hh][n][m], 0, 0, 0);
        }
    // spill scaled scores (lane holds 4 consecutive k for fixed q)
#pragma unroll
    for (int hh = 0; hh < 2; ++hh)
#pragma unroll
      for (int n = 0; n < 2; ++n)
#pragma unroll
        for (int m = 0; m < 2; ++m) {
          ushort4 pk = { f2bf(sa[hh][n][m][0] * 0.125f), f2bf(sa[hh][n][m][1] * 0.125f),
                         f2bf(sa[hh][n][m][2] * 0.125f), f2bf(sa[hh][n][m][3] * 0.125f) };
          *(ushort4*)&Ws[(h0 + hh) * 1024 + (m * 16 + lr) * 32 + n * 16 + lg * 4] = pk;
        }
    __syncthreads();  // barrier 1: spill visible

    // ---- P2: issue stage(t+1 -> other buf); softmax fibers ----
#pragma unroll
    for (int i = 0; i < 8; ++i) {
      gl16(kaddr[i], KsN + (i * 512 + t) * 8);
      kaddr[i] += 32;
    }
    {
      u16* fib = Ws + sq * 32 + sk * 2;
      float xa[16], xb[16];
#pragma unroll
      for (int h = 0; h < 16; ++h) {
        const unsigned u = *(const unsigned*)(fib + h * 1024);
        xa[h] = bf2f((u16)(u & 0xffffu));
        xb[h] = bf2f((u16)(u >> 16));
      }
      dsm16(xa);
      dsm16(xb);
#pragma unroll
      for (int h = 0; h < 16; ++h)
        *(unsigned*)(fib + h * 1024) = (unsigned)f2bf(xa[h]) | ((unsigned)f2bf(xb[h]) << 16);
    }
    __syncthreads();  // barrier 2: softmax visible; staging drained

    // ---- P3: PV from Ws + vfr ----
#pragma unroll
    for (int hh = 0; hh < 2; ++hh) {
      bf16x8 aw[2];
#pragma unroll
      for (int m = 0; m < 2; ++m)
        aw[m] = *(const bf16x8*)&Ws[(h0 + hh) * 1024 + (m * 16 + lr) * 32 + lg * 8];
#pragma unroll
      for (int ds = 0; ds < 4; ++ds) {
#pragma unroll
        for (int m = 0; m < 2; ++m)
          o[hh][m][ds] = __builtin_amdgcn_mfma_f32_16x16x32_bf16(aw[m], vfr[hh * 4 + ds],
                                                                 o[hh][m][ds], 0, 0, 0);
      }
    }
    __syncthreads();  // barrier 3: Ws reads done before next spill
  }

  // ---- epilogue ----
#pragma unroll
  for (int hh = 0; hh < 2; ++hh)
#pragma unroll
    for (int m = 0; m < 2; ++m)
#pragma unroll
      for (int ds = 0; ds < 4; ++ds)
#pragma unroll
        for (int r = 0; r < 4; ++r)
          AO[((size_t)b * SS + q0 + m * 16 + lg * 4 + r) * DM + (h0 + hh) * 64 + ds * 16 + lr] =
              f2bf(o[hh][m][ds][r]);
}

extern "C" void kernel_launch(void* const* d_in, const int* in_sizes, int n_in,
                              void* d_out, int out_size, void* d_ws, size_t ws_size,
                              hipStream_t stream) {
  const float* kin = (const float*)d_in[0];
  const float* qin = (const float*)d_in[1];
  const float* vin = (const float*)d_in[2];
  const float* Wq  = (const float*)d_in[3];
  const float* bq  = (const float*)d_in[4];
  const float* Wk  = (const float*)d_in[5];
  const float* bk  = (const float*)d_in[6];
  const float* Wv  = (const float*)d_in[7];
  const float* bv  = (const float*)d_in[8];
  const float* Wo  = (const float*)d_in[9];
  const float* bo  = (const float*)d_in[10];

  const size_t P   = (size_t)BB * SS * DM;   // 8388608
  const size_t WSZ = (size_t)DM * DM;
  u16* Qb  = (u16*)d_ws;
  u16* Kb  = Qb + P;
  u16* Vb  = Kb + P;
  u16* Wqb = Vb + P;
  u16* Wkb = Wqb + WSZ;
  u16* Wvb = Wkb + WSZ;
  u16* Wob = Wvb + WSZ;
  u16* Qp  = Wob + WSZ;
  u16* Kp  = Qp + P;
  u16* Vt  = Kp + P;     // [b,h,d,s]
  u16* AO  = Vt + P;

  cvt_bf16<<<dim3(4096), 256, 0, stream>>>(qin, Qb, (int)(P / 8));
  cvt_bf16<<<dim3(4096), 256, 0, stream>>>(kin, Kb, (int)(P / 8));
  cvt_bf16<<<dim3(4096), 256, 0, stream>>>(vin, Vb, (int)(P / 8));
  cvt_bf16<<<dim3(512), 256, 0, stream>>>(Wq, Wqb, (int)(WSZ / 8));
  cvt_bf16<<<dim3(512), 256, 0, stream>>>(Wk, Wkb, (int)(WSZ / 8));
  cvt_bf16<<<dim3(512), 256, 0, stream>>>(Wv, Wvb, (int)(WSZ / 8));
  cvt_bf16<<<dim3(512), 256, 0, stream>>>(Wo, Wob, (int)(WSZ / 8));

  dim3 gp(64, 8);
  gemm_proj<0><<<gp, 256, 0, stream>>>(Qb, Wqb, bq, Qp, 8192, 1024, 1024);
  gemm_proj<0><<<gp, 256, 0, stream>>>(Kb, Wkb, bk, Kp, 8192, 1024, 1024);
  gemm_proj<1><<<gp, 256, 0, stream>>>(Vb, Wvb, bv, Vt, 8192, 1024, 1024);

  fused_attn<<<dim3(256), 512, 0, stream>>>(Qp, Kp, Vt, AO);

  gemm_proj<2><<<gp, 256, 0, stream>>>(AO, Wob, bo, (float*)d_out, 8192, 1024, 1024);
}